// Round 1
// baseline (448.881 us; speedup 1.0000x reference)
//
#include <hip/hip_runtime.h>
#include <hip/hip_bf16.h>

typedef __attribute__((ext_vector_type(4))) float f32x4;
typedef __attribute__((ext_vector_type(8))) short short8;

#define NEG_BIG -9e15f

__device__ __forceinline__ short f2bf(float f) {
    unsigned u = __builtin_bit_cast(unsigned, f);
    u += 0x7fffu + ((u >> 16) & 1u);           // RNE to bf16
    return (short)(unsigned short)(u >> 16);
}

// Pre-kernel: Wt bf16 [o=128][f=128] (o-major) + wa_src/wa_dst = W @ a (fp32 exact)
__global__ void gat_pre(const float* __restrict__ W, const float* __restrict__ a_src,
                        const float* __restrict__ a_dst, unsigned short* __restrict__ wt,
                        float* __restrict__ wa) {
    int b = blockIdx.x, t = threadIdx.x;
    if (b < 64) {
        int e = b * 256 + t;            // 16384 elements
        int f = e >> 7, o = e & 127;
        wt[o * 128 + f] = (unsigned short)f2bf(W[f * 128 + o]);
    } else if (t < 128) {
        int f = t;
        float s1 = 0.f, s2 = 0.f;
        for (int o = 0; o < 128; ++o) {
            float w = W[f * 128 + o];
            s1 += w * a_src[o];
            s2 += w * a_dst[o];
        }
        wa[f] = s1; wa[128 + f] = s2;
    }
}

// Main fused kernel: 256 threads, 4 batches per tile (1 batch per wave, rows 16g+n)
__global__ __launch_bounds__(256, 2) void gat_main(
    const float* __restrict__ x, const int* __restrict__ adj,
    const unsigned short* __restrict__ wt, const float* __restrict__ wa,
    float* __restrict__ out, int ntiles)
{
    __shared__ __align__(16) float Ah[64 * 132];   // x tile (f32) then h (f32), stride 132
    __shared__ float att[4 * 15 * 16];             // per-batch 15x16 (j padded)
    __shared__ float s_src[64], s_dst[64];

    const int t = threadIdx.x;
    const int wv = t >> 6;          // wave = batch within tile
    const int lane = t & 63;
    const int l15 = lane & 15, lq = lane >> 4;

    // W fragments resident in registers for the whole kernel (32 x short8 = 128 VGPR)
    short8 bfr[4][8];
#pragma unroll
    for (int kk = 0; kk < 4; ++kk)
#pragma unroll
        for (int ct = 0; ct < 8; ++ct) {
            int col = ct * 16 + l15;
            int kb = kk * 32 + lq * 8;
            bfr[kk][ct] = *(const short8*)(wt + col * 128 + kb);
        }

    const float* wsrc = wa;
    const float* wdst = wa + 128;

    for (int tile = blockIdx.x; tile < ntiles; tile += gridDim.x) {
        const int bbase = tile * 4;

        // ---- stage x -> Ah (f32), rows = 16*g + n, pad rows zeroed
        {
            const float* xb = x + (size_t)bbase * 15 * 128;
#pragma unroll
            for (int i = 0; i < 9; ++i) {
                int idx = t + 256 * i;             // float4 index, 64*33 = 2112 total
                if (idx < 2112) {
                    int row = idx / 33;
                    int c4 = idx - row * 33;
                    if (c4 < 32) {
                        int g = row >> 4, n = row & 15;
                        float4 v;
                        if (n < 15) v = *(const float4*)(xb + (g * 15 + n) * 128 + c4 * 4);
                        else        v = make_float4(0.f, 0.f, 0.f, 0.f);
                        *(float4*)&Ah[row * 132 + c4 * 4] = v;
                    }
                }
            }
        }
        // adj prefetch for e-phase (hide latency under GEMM)
        int adjv[4];
#pragma unroll
        for (int m = 0; m < 4; ++m) {
            int p = lane + 64 * m;
            adjv[m] = (p < 225) ? adj[(size_t)(bbase + wv) * 225 + p] : 0;
        }
        __syncthreads();

        // ---- GEMM: wave wv computes h rows 16wv..16wv+15 (bf16 MFMA, f32 acc)
        f32x4 acc[8];
#pragma unroll
        for (int ct = 0; ct < 8; ++ct) acc[ct] = (f32x4){0.f, 0.f, 0.f, 0.f};
#pragma unroll
        for (int kk = 0; kk < 4; ++kk) {
            int kb = kk * 32 + lq * 8;
            const float* ap = &Ah[(16 * wv + l15) * 132 + kb];
            float4 a0 = *(const float4*)ap;
            float4 a1 = *(const float4*)(ap + 4);
            short8 af;
            af[0] = f2bf(a0.x); af[1] = f2bf(a0.y); af[2] = f2bf(a0.z); af[3] = f2bf(a0.w);
            af[4] = f2bf(a1.x); af[5] = f2bf(a1.y); af[6] = f2bf(a1.z); af[7] = f2bf(a1.w);
#pragma unroll
            for (int ct = 0; ct < 8; ++ct)
                acc[ct] = __builtin_amdgcn_mfma_f32_16x16x32_bf16(af, bfr[kk][ct], acc[ct], 0, 0, 0);
        }

        // ---- s-phase: exact fp32 s = x . (W @ a) for this wave's rows
        {
            float ps = 0.f, pd = 0.f;
            const float* ar = &Ah[(16 * wv + l15) * 132 + lq * 32];
            const float* w1 = wsrc + lq * 32;
            const float* w2 = wdst + lq * 32;
#pragma unroll
            for (int j = 0; j < 8; ++j) {
                float4 av = *(const float4*)(ar + 4 * j);
                float4 u1 = *(const float4*)(w1 + 4 * j);
                float4 u2 = *(const float4*)(w2 + 4 * j);
                ps += av.x * u1.x + av.y * u1.y + av.z * u1.z + av.w * u1.w;
                pd += av.x * u2.x + av.y * u2.y + av.z * u2.z + av.w * u2.w;
            }
            ps += __shfl_xor(ps, 16); pd += __shfl_xor(pd, 16);
            ps += __shfl_xor(ps, 32); pd += __shfl_xor(pd, 32);
            if (lq == 0) { s_src[16 * wv + l15] = ps; s_dst[16 * wv + l15] = pd; }
        }
        __syncthreads();

        // ---- write h (f32) over the x region (C/D layout: col=lane&15, row=lq*4+r)
#pragma unroll
        for (int ct = 0; ct < 8; ++ct) {
            int col = ct * 16 + l15;
#pragma unroll
            for (int r = 0; r < 4; ++r) {
                int row = 16 * wv + lq * 4 + r;
                Ah[row * 132 + col] = acc[ct][r];
            }
        }
        __syncthreads();

        // ---- e-phase: masked leaky-relu logits (batch = wv)
#pragma unroll
        for (int m = 0; m < 4; ++m) {
            int p = lane + 64 * m;
            if (p < 225) {
                int i = p / 15, j = p - i * 15;
                float e = s_src[16 * wv + i] + s_dst[16 * wv + j];
                e = e > 0.f ? e : 0.2f * e;
                e = adjv[m] > 0 ? e : NEG_BIG;
                att[(wv * 15 + i) * 16 + j] = e;
            }
        }
        __syncthreads();

        // ---- softmax over i (axis=1) per (g, j): 60 threads
        if (t < 60) {
            int g = t / 15, j = t - (t / 15) * 15;
            float m = att[(g * 15 + 0) * 16 + j];
#pragma unroll
            for (int i = 1; i < 15; ++i) m = fmaxf(m, att[(g * 15 + i) * 16 + j]);
            float ssum = 0.f;
            float ev[15];
#pragma unroll
            for (int i = 0; i < 15; ++i) {
                ev[i] = __expf(att[(g * 15 + i) * 16 + j] - m);
                ssum += ev[i];
            }
            float inv = 1.f / ssum;
#pragma unroll
            for (int i = 0; i < 15; ++i) att[(g * 15 + i) * 16 + j] = ev[i] * inv;
        }
        __syncthreads();

        // ---- PV + elu + coalesced store: thread = (o, batch-group)
        {
            int o = t & 127, grp = t >> 7;
#pragma unroll
            for (int gg = 0; gg < 2; ++gg) {
                int g = grp + 2 * gg;
                float h[15];
#pragma unroll
                for (int j = 0; j < 15; ++j) h[j] = Ah[(16 * g + j) * 132 + o];
                float* ob = out + (size_t)(bbase + g) * 15 * 128 + o;
#pragma unroll
                for (int i = 0; i < 15; ++i) {
                    float a = 0.f;
#pragma unroll
                    for (int j = 0; j < 15; ++j) a += att[(g * 15 + i) * 16 + j] * h[j];
                    a = a > 0.f ? a : (__expf(a) - 1.f);
                    ob[i * 128] = a;
                }
            }
        }
        __syncthreads();   // protect Ah/att/s before next tile's staging
    }
}

extern "C" void kernel_launch(void* const* d_in, const int* in_sizes, int n_in,
                              void* d_out, int out_size, void* d_ws, size_t ws_size,
                              hipStream_t stream) {
    const float* x     = (const float*)d_in[0];
    const int*   adj   = (const int*)d_in[1];
    const float* W     = (const float*)d_in[2];
    const float* a_src = (const float*)d_in[3];
    const float* a_dst = (const float*)d_in[4];
    float* out = (float*)d_out;

    unsigned short* wt = (unsigned short*)d_ws;
    float* wa = (float*)((char*)d_ws + 32768);

    int B = in_sizes[0] / (15 * 128);
    int ntiles = B / 4;

    gat_pre<<<65, 256, 0, stream>>>(W, a_src, a_dst, wt, wa);
    gat_main<<<1024, 256, 0, stream>>>(x, adj, wt, wa, out, ntiles);
}

// Round 2
// 246.283 us; speedup vs baseline: 1.8226x; 1.8226x over previous
//
#include <hip/hip_runtime.h>
#include <hip/hip_bf16.h>

typedef __attribute__((ext_vector_type(4))) float f32x4;
typedef __attribute__((ext_vector_type(8))) short short8;
typedef __attribute__((ext_vector_type(4))) _Float16 f16x4;

#define NEG_BIG -9e15f

__device__ __forceinline__ short f2bf(float f) {
    unsigned u = __builtin_bit_cast(unsigned, f);
    u += 0x7fffu + ((u >> 16) & 1u);           // RNE to bf16
    return (short)(unsigned short)(u >> 16);
}

// Pre-kernel: W -> bf16 B-fragment layout (16x16x32 MFMA) + wa = W @ a (fp32 exact)
// frag layout: element ((kk*8+ct)*64 + lane)*8 + jj  =  bf16(W[kk*32 + (lane>>4)*8 + jj][ct*16 + (lane&15)])
__global__ void gat_pre(const float* __restrict__ W, const float* __restrict__ a_src,
                        const float* __restrict__ a_dst, unsigned short* __restrict__ wt,
                        float* __restrict__ wa) {
    int blk = blockIdx.x, t = threadIdx.x;
    if (blk < 8) {
        int e = blk * 256 + t;              // e = (kk*8+ct)*64 + lane
        int kk = e >> 9, ct = (e >> 6) & 7, lane = e & 63;
        int lq = lane >> 4, l15 = lane & 15;
        short8 v;
#pragma unroll
        for (int jj = 0; jj < 8; ++jj)
            v[jj] = f2bf(W[(kk * 32 + lq * 8 + jj) * 128 + ct * 16 + l15]);
        *(short8*)(wt + (size_t)e * 8) = v;
    } else if (t < 128) {
        float s1 = 0.f, s2 = 0.f;
        for (int o = 0; o < 128; ++o) {
            float w = W[t * 128 + o];
            s1 += w * a_src[o];
            s2 += w * a_dst[o];
        }
        wa[t] = s1; wa[128 + t] = s2;
    }
}

__device__ __forceinline__ void load_batch(const float* __restrict__ x,
                                           const int* __restrict__ adj,
                                           int b, int lq, int l15,
                                           float4 (&xv)[8], int (&av)[4]) {
    const float* xb = x + (size_t)b * 1920 + l15 * 128 + lq * 8;
#pragma unroll
    for (int kk = 0; kk < 4; ++kk) {
        if (l15 < 15) {
            xv[2 * kk]     = *(const float4*)(xb + kk * 32);
            xv[2 * kk + 1] = *(const float4*)(xb + kk * 32 + 4);
        } else {
            xv[2 * kk]     = make_float4(0.f, 0.f, 0.f, 0.f);
            xv[2 * kk + 1] = make_float4(0.f, 0.f, 0.f, 0.f);
        }
    }
    const int* ab = adj + (size_t)b * 225 + l15 * 15 + lq * 4;
#pragma unroll
    for (int r = 0; r < 4; ++r)
        av[r] = (l15 < 15 && lq * 4 + r < 15) ? ab[r] : 0;
}

// s-partials (exact fp32, lane's 32 columns) + bf16 A-fragment conversion
__device__ __forceinline__ void prep(const float4 (&xv)[8], const float* __restrict__ walds,
                                     int lq, float& ps, float& pd, short8 (&af)[4]) {
    ps = 0.f; pd = 0.f;
#pragma unroll
    for (int kk = 0; kk < 4; ++kk) {
        float4 a0 = xv[2 * kk], a1 = xv[2 * kk + 1];
        const float* wb = walds + kk * 32 + lq * 8;
        float4 s0 = *(const float4*)(wb);
        float4 s1 = *(const float4*)(wb + 4);
        float4 d0 = *(const float4*)(wb + 128);
        float4 d1 = *(const float4*)(wb + 132);
        ps += a0.x * s0.x + a0.y * s0.y + a0.z * s0.z + a0.w * s0.w
            + a1.x * s1.x + a1.y * s1.y + a1.z * s1.z + a1.w * s1.w;
        pd += a0.x * d0.x + a0.y * d0.y + a0.z * d0.z + a0.w * d0.w
            + a1.x * d1.x + a1.y * d1.y + a1.z * d1.z + a1.w * d1.w;
        short8 c;
        c[0] = f2bf(a0.x); c[1] = f2bf(a0.y); c[2] = f2bf(a0.z); c[3] = f2bf(a0.w);
        c[4] = f2bf(a1.x); c[5] = f2bf(a1.y); c[6] = f2bf(a1.z); c[7] = f2bf(a1.w);
        af[kk] = c;
    }
}

// walds layout: [0..127] = W@a_src, [128..255] = W@a_dst  (prep reads wb+128/wb+132)
__global__ __launch_bounds__(256, 4) void gat_main(
    const float* __restrict__ x, const int* __restrict__ adj,
    const unsigned short* __restrict__ wfrag, const float* __restrict__ wa,
    float* __restrict__ out, int B)
{
    __shared__ __align__(16) unsigned short wlds[16384];   // 32 KB W fragments
    __shared__ __align__(16) float walds[256];             // 1 KB wa

    const int t = threadIdx.x;
    const int lane = t & 63;
    const int lq = lane >> 4, l15 = lane & 15;

#pragma unroll
    for (int i = 0; i < 8; ++i)
        *(float4*)((char*)wlds + (t + 256 * i) * 16) =
            *(const float4*)((const char*)wfrag + (t + 256 * i) * 16);
    if (t < 64)
        *(float4*)(walds + t * 4) = *(const float4*)(wa + t * 4);
    __syncthreads();   // only barrier in the kernel; waves independent after this

    const int wid = blockIdx.x * 4 + (t >> 6);
    const int stride = gridDim.x * 4;

    float4 xr[8];
    int adjr[4];
    short8 af[4];
    float ps = 0.f, pd = 0.f;
    int adjc[4] = {0, 0, 0, 0};

    if (wid < B) {
        load_batch(x, adj, wid, lq, l15, xr, adjr);
        prep(xr, walds, lq, ps, pd, af);
#pragma unroll
        for (int r = 0; r < 4; ++r) adjc[r] = adjr[r];
    }

    for (int b = wid; b < B; b += stride) {
        const int bn = b + stride;
        const bool pn = bn < B;
        if (pn) load_batch(x, adj, bn, lq, l15, xr, adjr);   // prefetch next batch

        // reduce s over the 4 lq-lanes: every lane gets ss[i=l15], sd[i=l15]
        float ss = ps + __shfl_xor(ps, 16);
        ss += __shfl_xor(ss, 32);
        float sd = pd + __shfl_xor(pd, 16);
        sd += __shfl_xor(sd, 32);

        // h = x @ W : 32 MFMA, W B-fragments streamed from LDS
        f32x4 acc[8];
#pragma unroll
        for (int ct = 0; ct < 8; ++ct) acc[ct] = (f32x4){0.f, 0.f, 0.f, 0.f};
#pragma unroll
        for (int kk = 0; kk < 4; ++kk) {
#pragma unroll
            for (int ct = 0; ct < 8; ++ct) {
                short8 bf = *(const short8*)(wlds + ((size_t)(kk * 8 + ct) * 64 + lane) * 8);
                acc[ct] = __builtin_amdgcn_mfma_f32_16x16x32_bf16(af[kk], bf, acc[ct], 0, 0, 0);
            }
        }

        // softmax over i (axis=1): rows i = l15, this lane's columns j = lq*4+r
        float attv[4];
#pragma unroll
        for (int r = 0; r < 4; ++r) {
            float sdj = __shfl(sd, lq * 4 + r);
            float e = ss + sdj;
            e = e > 0.f ? e : 0.2f * e;             // leaky relu BEFORE mask (matches ref)
            e = adjc[r] > 0 ? e : NEG_BIG;
            if (l15 == 15) e = -INFINITY;           // pad row excluded exactly
            float m = e;
            m = fmaxf(m, __shfl_xor(m, 1));
            m = fmaxf(m, __shfl_xor(m, 2));
            m = fmaxf(m, __shfl_xor(m, 4));
            m = fmaxf(m, __shfl_xor(m, 8));
            float ev = __expf(e - m);
            float sm = ev;
            sm += __shfl_xor(sm, 1);
            sm += __shfl_xor(sm, 2);
            sm += __shfl_xor(sm, 4);
            sm += __shfl_xor(sm, 8);
            attv[r] = ev * __builtin_amdgcn_rcpf(sm);
        }

        // PV via 16x16x16 f16 MFMA: att is already A-frag (row=l15, k=lq*4+jj),
        // h acc (row=lq*4+r) is already B-frag (k=lq*4+jj) -> zero redistribution
        f16x4 ha;
        ha[0] = (_Float16)attv[0]; ha[1] = (_Float16)attv[1];
        ha[2] = (_Float16)attv[2]; ha[3] = (_Float16)attv[3];

        float* ob = out + (size_t)b * 1920 + l15;
        const f32x4 z4 = {0.f, 0.f, 0.f, 0.f};
#pragma unroll
        for (int ct = 0; ct < 8; ++ct) {
            f16x4 hb;
            hb[0] = (_Float16)acc[ct][0]; hb[1] = (_Float16)acc[ct][1];
            hb[2] = (_Float16)acc[ct][2]; hb[3] = (_Float16)acc[ct][3];
            f32x4 o4 = __builtin_amdgcn_mfma_f32_16x16x16f16(ha, hb, z4, 0, 0, 0);
#pragma unroll
            for (int r = 0; r < 4; ++r) {
                const int row = lq * 4 + r;
                if (row < 15) {
                    float v = o4[r];
                    v = v > 0.f ? v : (__expf(v) - 1.f);   // elu
                    ob[row * 128 + ct * 16] = v;
                }
            }
        }

        // fold prefetched batch into pipeline state (waitcnt lands here, ~full iter after issue)
        if (pn) {
            prep(xr, walds, lq, ps, pd, af);
#pragma unroll
            for (int r = 0; r < 4; ++r) adjc[r] = adjr[r];
        }
    }
}

extern "C" void kernel_launch(void* const* d_in, const int* in_sizes, int n_in,
                              void* d_out, int out_size, void* d_ws, size_t ws_size,
                              hipStream_t stream) {
    const float* x     = (const float*)d_in[0];
    const int*   adj   = (const int*)d_in[1];
    const float* W     = (const float*)d_in[2];
    const float* a_src = (const float*)d_in[3];
    const float* a_dst = (const float*)d_in[4];
    float* out = (float*)d_out;

    unsigned short* wt = (unsigned short*)d_ws;
    float* wa = (float*)((char*)d_ws + 32768);

    int B = in_sizes[0] / (15 * 128);

    gat_pre<<<9, 256, 0, stream>>>(W, a_src, a_dst, wt, wa);
    gat_main<<<1024, 256, 0, stream>>>(x, adj, wt, wa, out, B);
}